// Round 3
// baseline (186.501 us; speedup 1.0000x reference)
//
#include <hip/hip_runtime.h>
#include <hip/hip_bf16.h>

// Problem constants (hardcoded from setup_inputs; n_shifts == T == 64)
#define NB   4096
#define NT   64
#define NDIM 16
#define NH1  256
#define NH2  256
#define NLAT 64
#define NKD  80
#define YROW (NT * NKD)      // 5120 floats per batch row of y / y_pred
#define KTAB 98304           // short-offset of K-power fragment table in ws
#define KSLOT 15360          // shorts per t-slot (7680 hi + 7680 lo)

typedef __attribute__((ext_vector_type(8))) short bf16x8;
typedef __attribute__((ext_vector_type(4))) float f32x4;

#define MFMA __builtin_amdgcn_mfma_f32_16x16x32_bf16

static __device__ __forceinline__ short f2bf(float f) {
  union { float f; unsigned u; } v; v.f = f;
  unsigned r = v.u + 0x7fffu + ((v.u >> 16) & 1u);   // RNE
  return (short)(r >> 16);
}
static __device__ __forceinline__ float bf2f(short h) {
  union { unsigned u; float f; } v; v.u = ((unsigned)(unsigned short)h) << 16;
  return v.f;
}
static __device__ __forceinline__ bf16x8 pack8(float4 a, float4 b) {
  bf16x8 r;
  r[0] = f2bf(a.x); r[1] = f2bf(a.y); r[2] = f2bf(a.z); r[3] = f2bf(a.w);
  r[4] = f2bf(b.x); r[5] = f2bf(b.y); r[6] = f2bf(b.z); r[7] = f2bf(b.w);
  return r;
}
static __device__ __forceinline__ void split8(float4 v0, float4 v1, bf16x8& h, bf16x8& l) {
  h = pack8(v0, v1);
  float4 r0, r1;
  r0.x = v0.x - bf2f(h[0]); r0.y = v0.y - bf2f(h[1]);
  r0.z = v0.z - bf2f(h[2]); r0.w = v0.w - bf2f(h[3]);
  r1.x = v1.x - bf2f(h[4]); r1.y = v1.y - bf2f(h[5]);
  r1.z = v1.z - bf2f(h[6]); r1.w = v1.w - bf2f(h[7]);
  l = pack8(r0, r1);
}

// ---------------------------------------------------------------------------
// Prep: rearrange weights into MFMA B-fragment order (bf16) in workspace.
// B-frag: lane l holds B[k][n], n = l&15, k = 8*(l>>4)+e. B = W^T.
// ws (shorts): [0) W2f 65536 | [65536) W3f 16384 | [81920) W1f 8192
// ---------------------------------------------------------------------------
__global__ __launch_bounds__(256) void prep_kernel(const float* __restrict__ W1,
                                                   const float* __restrict__ W2,
                                                   const float* __restrict__ W3,
                                                   short* __restrict__ ws) {
  int i = blockIdx.x * 256 + threadIdx.x;   // 0..65535
  {
    int e = i & 7, l = (i >> 3) & 63, nt = (i >> 9) & 15, kk = i >> 13;
    int g = nt * 16 + (l & 15);
    int h = kk * 32 + (l >> 4) * 8 + e;
    ws[i] = f2bf(W2[g * NH1 + h]);
  }
  if (i < 16384) {
    int e = i & 7, l = (i >> 3) & 63, nt = (i >> 9) & 3, kk = i >> 11;
    int g = nt * 16 + (l & 15);
    int h = kk * 32 + (l >> 4) * 8 + e;
    ws[65536 + i] = f2bf(W3[g * NH2 + h]);
  }
  if (i < 8192) {
    int e = i & 7, l = (i >> 3) & 63, nt = i >> 9;
    int g = nt * 16 + (l & 15);
    int k = (l >> 4) * 8 + e;
    ws[81920 + i] = (k < NDIM) ? f2bf(W1[g * NDIM + k]) : (short)0;
  }
}

// ---------------------------------------------------------------------------
// Fused kernel, 512 threads:
//  blocks 0..63   : kpow — block t computes K^t (f32, binary exponentiation in
//                   LDS) and writes hi/lo split-bf16 B-fragments to ws.
//                   Runs concurrently with (hidden under) the MLP blocks.
//  blocks 64..2111: MLP — 2 batch rows (128 tokens), 8 waves.
//    GEMM1/2 wave split: mh = w&1 (4 M-tiles), ng = w>>1 (4 N-tiles).
//    B-frags from global (L2), next-kk register prefetch in GEMM2.
//    LDS: h1s [128][264] bf16 (67584 B); h2s overlays h1s; ys overlays.
//    -> 2 blocks/CU (135 KB), 16 waves/CU.
// ---------------------------------------------------------------------------
__global__ __launch_bounds__(512, 4) void fused_kernel(const float* __restrict__ x,
                                                       const float* __restrict__ b1g,
                                                       const float* __restrict__ b2g,
                                                       short* __restrict__ ws,
                                                       const float* __restrict__ Kg,
                                                       float* __restrict__ y) {
  extern __shared__ char smem[];
  const int tid = threadIdx.x;

  if (blockIdx.x < 64) {
    // ------------------------- kpow -------------------------
    const int t = blockIdx.x;
    if (t == 0) return;
    float* R0 = (float*)smem;            // 25600 B
    float* R1 = (float*)(smem + 25600);  // 25600 B
    for (int i = tid; i < 6400; i += 512) R0[i] = Kg[i];
    __syncthreads();
    float* cur = R0;
    float* nxt = R1;
    const int c  = tid % 80;
    const int rg = tid / 80;
    const bool act = tid < 480;

    auto mm = [&](const float* A, const float* Blds, bool bGlobal, float* D) {
      if (act) {
        float bcol[80];
        if (bGlobal) {
#pragma unroll
          for (int j = 0; j < 80; ++j) bcol[j] = Kg[j * 80 + c];
        } else {
#pragma unroll
          for (int j = 0; j < 80; ++j) bcol[j] = Blds[j * 80 + c];
        }
        for (int r = rg; r < 80; r += 6) {
          float s0 = 0.f, s1 = 0.f, s2 = 0.f, s3 = 0.f;
#pragma unroll
          for (int j = 0; j < 20; ++j) {
            float4 av = *(const float4*)(A + r * 80 + j * 4);
            s0 += av.x * bcol[j * 4 + 0];
            s1 += av.y * bcol[j * 4 + 1];
            s2 += av.z * bcol[j * 4 + 2];
            s3 += av.w * bcol[j * 4 + 3];
          }
          D[r * 80 + c] = (s0 + s1) + (s2 + s3);
        }
      }
      __syncthreads();
    };

    const int h = 31 - __clz(t);
    for (int bit = h - 1; bit >= 0; --bit) {
      mm(cur, cur, false, nxt);                     // square
      { float* tmp = cur; cur = nxt; nxt = tmp; }
      if ((t >> bit) & 1) {
        mm(cur, nullptr, true, nxt);                // multiply by K
        { float* tmp = cur; cur = nxt; nxt = tmp; }
      }
    }
    // write hi/lo split B-frag table: B[k][n] = (K^t)[n][k]
    short* kt = ws + KTAB + t * KSLOT;
    for (int idx = tid; idx < 7680; idx += 512) {
      int e = idx & 7, ln = (idx >> 3) & 63, rem = idx >> 9;   // rem = kk*5+nt
      int kk = rem / 5, nt = rem % 5;
      int k = kk * 32 + (ln >> 4) * 8 + e;
      int n = nt * 16 + (ln & 15);
      float v = (k < 80) ? cur[n * 80 + k] : 0.f;
      short hi = f2bf(v);
      kt[idx] = hi;
      kt[7680 + idx] = f2bf(v - bf2f(hi));
    }
    return;
  }

  // ------------------------- MLP -------------------------
  short* h1s = (short*)smem;            // [128][264] bf16; h2s overlays
  float* ys  = (float*)smem;            // [128][80] f32 overlay

  const int lane = tid & 63;
  const int w    = tid >> 6;            // 0..7
  const int m16  = lane & 15;
  const int kg   = lane >> 4;
  const long b   = blockIdx.x - 64;     // 0..2047 (2 batch rows each)
  const int mh   = w & 1;               // M-half
  const int ng   = w >> 1;              // N-quarter

  const short* W2f = ws;
  const short* W3f = ws + 65536;
  const short* W1f = ws + 81920;

  const float4 xv = ((const float4*)(x + b * 2048))[tid];   // for y epilogue

  // ---- GEMM1: h1 = relu(x @ W1^T + b1); A-frags direct from global ----
  bf16x8 a1[4];
#pragma unroll
  for (int mt = 0; mt < 4; ++mt) {
    bf16x8 f = {};
    if (kg < 2) {
      const float4* xp =
          (const float4*)(x + (b * 128 + (mh * 4 + mt) * 16 + m16) * 16 + kg * 8);
      f = pack8(xp[0], xp[1]);
    }
    a1[mt] = f;
  }
#pragma unroll
  for (int nt = 0; nt < 4; ++nt) {
    const int n = ng * 4 + nt;
    const bf16x8 bb = *(const bf16x8*)(W1f + (n * 64 + lane) * 8);
    const float bias = b1g[n * 16 + m16];
#pragma unroll
    for (int mt = 0; mt < 4; ++mt) {
      f32x4 cc = {0.f, 0.f, 0.f, 0.f};
      cc = MFMA(a1[mt], bb, cc, 0, 0, 0);
      short* row = h1s + ((mh * 4 + mt) * 16 + kg * 4) * 264 + n * 16 + m16;
#pragma unroll
      for (int r = 0; r < 4; ++r) {
        float v = cc[r] + bias;
        v = v > 0.f ? v : 0.f;
        row[r * 264] = f2bf(v);
      }
    }
  }
  __syncthreads();

  // ---- GEMM2: h2 = relu(h1 @ W2^T + b2); K=256; prefetched B-frags ----
  f32x4 acc2[4][4];
#pragma unroll
  for (int mt = 0; mt < 4; ++mt)
#pragma unroll
    for (int nt = 0; nt < 4; ++nt) acc2[mt][nt] = (f32x4){0.f, 0.f, 0.f, 0.f};

  bf16x8 bc[4], bn[4];
#pragma unroll
  for (int nt = 0; nt < 4; ++nt)
    bc[nt] = *(const bf16x8*)(W2f + ((ng * 4 + nt) * 64 + lane) * 8);

  for (int kk = 0; kk < 8; ++kk) {
    const bool pf = kk < 7;
    if (pf) {
#pragma unroll
      for (int nt = 0; nt < 4; ++nt)
        bn[nt] = *(const bf16x8*)(W2f + (((kk + 1) * 16 + ng * 4 + nt) * 64 + lane) * 8);
    }
#pragma unroll
    for (int mt = 0; mt < 4; ++mt) {
      const bf16x8 a =
          *(const bf16x8*)(h1s + ((mh * 4 + mt) * 16 + m16) * 264 + kk * 32 + kg * 8);
#pragma unroll
      for (int nt = 0; nt < 4; ++nt)
        acc2[mt][nt] = MFMA(a, bc[nt], acc2[mt][nt], 0, 0, 0);
    }
    if (pf) {
#pragma unroll
      for (int nt = 0; nt < 4; ++nt) bc[nt] = bn[nt];
    }
  }
  __syncthreads();   // all h1 reads done -> overlay h2
  {
#pragma unroll
    for (int nt = 0; nt < 4; ++nt) {
      const int n = ng * 4 + nt;
      const float bias = b2g[n * 16 + m16];
#pragma unroll
      for (int mt = 0; mt < 4; ++mt) {
        short* row = h1s + ((mh * 4 + mt) * 16 + kg * 4) * 264 + n * 16 + m16;
#pragma unroll
        for (int r = 0; r < 4; ++r) {
          float v = acc2[mt][nt][r] + bias;
          v = v > 0.f ? v : 0.f;
          row[r * 264] = f2bf(v);
        }
      }
    }
  }
  __syncthreads();

  // ---- GEMM3: g = h2 @ W3^T; wave w -> ntile w&3, 4 mtiles ----
  const int nt3 = w & 3;
  const int mb  = (w >> 2) * 4;
  f32x4 acc3[4];
#pragma unroll
  for (int m = 0; m < 4; ++m) acc3[m] = (f32x4){0.f, 0.f, 0.f, 0.f};
  for (int kk = 0; kk < 8; ++kk) {
    const bf16x8 bb = *(const bf16x8*)(W3f + ((kk * 4 + nt3) * 64 + lane) * 8);
#pragma unroll
    for (int m = 0; m < 4; ++m) {
      const bf16x8 a =
          *(const bf16x8*)(h1s + ((mb + m) * 16 + m16) * 264 + kk * 32 + kg * 8);
      acc3[m] = MFMA(a, bb, acc3[m], 0, 0, 0);
    }
  }
  __syncthreads();   // all h2 reads done -> overlay ys

  // ---- assemble y tile: x part (exact f32 from regs) + g part ----
  {
    int t0 = tid >> 2, d0 = (tid & 3) * 4;
    *(float4*)(ys + t0 * 80 + d0) = xv;
  }
#pragma unroll
  for (int m = 0; m < 4; ++m)
#pragma unroll
    for (int r = 0; r < 4; ++r)
      ys[((mb + m) * 16 + kg * 4 + r) * 80 + 16 + nt3 * 16 + m16] = acc3[m][r];
  __syncthreads();

  float4* yg = (float4*)(y + b * (2 * YROW));
  const float4* ysv = (const float4*)ys;
#pragma unroll
  for (int i = 0; i < 5; ++i)
    yg[i * 512 + tid] = ysv[i * 512 + tid];
}

// ---------------------------------------------------------------------------
// ypred: y_pred[b, t, :] = y0[b] @ (K^t)^T via split-bf16 MFMA (~f32 accurate).
// grid = 16 batch-chunks (256 rows) x 32 t-groups (2 t each). 512 thr, 8 waves.
// Wave w owns M-tiles {2w, 2w+1}; A hi/lo frags built once in registers.
// t = 0 is a straight copy of y0.
// ---------------------------------------------------------------------------
__global__ __launch_bounds__(512, 4) void ypred_kernel(const short* __restrict__ ws,
                                                       const float* __restrict__ y,
                                                       float* __restrict__ yp) {
  const int tid  = threadIdx.x;
  const int lane = tid & 63;
  const int w    = tid >> 6;
  const int m16  = lane & 15;
  const int kg   = lane >> 4;
  const int bc   = blockIdx.x & 15;
  const int tg   = blockIdx.x >> 4;
  const long b0  = (long)bc * 256;

  // Build A hi/lo fragments from y0 (2 mt x 3 kk)
  bf16x8 ah[2][3], al[2][3];
#pragma unroll
  for (int m = 0; m < 2; ++m) {
#pragma unroll
    for (int kk = 0; kk < 3; ++kk) {
      const int k0 = kk * 32 + kg * 8;
      bf16x8 fh = {}, fl = {};
      if (k0 < 80) {
        const float4* p =
            (const float4*)(y + (b0 + (2 * w + m) * 16 + m16) * YROW + k0);
        split8(p[0], p[1], fh, fl);
      }
      ah[m][kk] = fh;
      al[m][kk] = fl;
    }
  }

  for (int tt = 0; tt < 2; ++tt) {
    const int t = tg * 2 + tt;
    if (t == 0) {
      for (int i = tid; i < 5120; i += 512) {
        int r = i / 20, q = (i % 20) * 4;
        *(float4*)(yp + (b0 + r) * YROW + q) = *(const float4*)(y + (b0 + r) * YROW + q);
      }
      continue;
    }
    const short* kt = ws + KTAB + t * KSLOT;
    f32x4 acc[2][5];
#pragma unroll
    for (int m = 0; m < 2; ++m)
#pragma unroll
      for (int nt = 0; nt < 5; ++nt) acc[m][nt] = (f32x4){0.f, 0.f, 0.f, 0.f};

#pragma unroll
    for (int kk = 0; kk < 3; ++kk) {
#pragma unroll
      for (int nt = 0; nt < 5; ++nt) {
        const bf16x8 bh = *(const bf16x8*)(kt + ((kk * 5 + nt) * 64 + lane) * 8);
        const bf16x8 bl = *(const bf16x8*)(kt + 7680 + ((kk * 5 + nt) * 64 + lane) * 8);
#pragma unroll
        for (int m = 0; m < 2; ++m) {
          acc[m][nt] = MFMA(ah[m][kk], bh, acc[m][nt], 0, 0, 0);
          acc[m][nt] = MFMA(al[m][kk], bh, acc[m][nt], 0, 0, 0);
          acc[m][nt] = MFMA(ah[m][kk], bl, acc[m][nt], 0, 0, 0);
        }
      }
    }
    // direct stores: 16 consecutive floats per (mt,nt,r) per 16-lane group
#pragma unroll
    for (int m = 0; m < 2; ++m)
#pragma unroll
      for (int nt = 0; nt < 5; ++nt)
#pragma unroll
        for (int r = 0; r < 4; ++r)
          yp[(b0 + (2 * w + m) * 16 + kg * 4 + r) * YROW + (long)t * 80 + nt * 16 + m16] =
              acc[m][nt][r];
  }
}

extern "C" void kernel_launch(void* const* d_in, const int* in_sizes, int n_in,
                              void* d_out, int out_size, void* d_ws, size_t ws_size,
                              hipStream_t stream) {
  const float* x  = (const float*)d_in[0];
  const float* W1 = (const float*)d_in[1];
  const float* b1 = (const float*)d_in[2];
  const float* W2 = (const float*)d_in[3];
  const float* b2 = (const float*)d_in[4];
  const float* W3 = (const float*)d_in[5];
  const float* Kg = (const float*)d_in[6];
  float* y  = (float*)d_out;
  float* yp = y + (long)NB * YROW;
  short* ws = (short*)d_ws;

  prep_kernel<<<256, 256, 0, stream>>>(W1, W2, W3, ws);
  fused_kernel<<<64 + NB / 2, 512, 67584, stream>>>(x, b1, b2, ws, Kg, y);
  ypred_kernel<<<512, 512, 0, stream>>>(ws, y, yp);
}

// Round 5
// 151.946 us; speedup vs baseline: 1.2274x; 1.2274x over previous
//
#include <hip/hip_runtime.h>
#include <hip/hip_bf16.h>

// Problem constants (hardcoded from setup_inputs; n_shifts == T == 64)
#define NB   4096
#define NT   64
#define NDIM 16
#define NH1  256
#define NH2  256
#define NLAT 64
#define NKD  80
#define YROW (NT * NKD)      // 5120 floats per batch row of y / y_pred

typedef __attribute__((ext_vector_type(8))) short bf16x8;
typedef __attribute__((ext_vector_type(4))) float f32x4;

#define MFMA __builtin_amdgcn_mfma_f32_16x16x32_bf16

static __device__ __forceinline__ short f2bf(float f) {
  union { float f; unsigned u; } v; v.f = f;
  unsigned r = v.u + 0x7fffu + ((v.u >> 16) & 1u);   // RNE
  return (short)(r >> 16);
}
static __device__ __forceinline__ float bf2f(short h) {
  union { unsigned u; float f; } v; v.u = ((unsigned)(unsigned short)h) << 16;
  return v.f;
}
static __device__ __forceinline__ bf16x8 pack8(float4 a, float4 b) {
  bf16x8 r;
  r[0] = f2bf(a.x); r[1] = f2bf(a.y); r[2] = f2bf(a.z); r[3] = f2bf(a.w);
  r[4] = f2bf(b.x); r[5] = f2bf(b.y); r[6] = f2bf(b.z); r[7] = f2bf(b.w);
  return r;
}
static __device__ __forceinline__ void split8(float4 v0, float4 v1, bf16x8& h, bf16x8& l) {
  h = pack8(v0, v1);
  float4 r0, r1;
  r0.x = v0.x - bf2f(h[0]); r0.y = v0.y - bf2f(h[1]);
  r0.z = v0.z - bf2f(h[2]); r0.w = v0.w - bf2f(h[3]);
  r1.x = v1.x - bf2f(h[4]); r1.y = v1.y - bf2f(h[5]);
  r1.z = v1.z - bf2f(h[6]); r1.w = v1.w - bf2f(h[7]);
  l = pack8(r0, r1);
}

// ---------------------------------------------------------------------------
// Prep: rearrange weights into MFMA B-fragment order (bf16) in workspace.
// B-frag: lane l holds B[k][n], n = l&15, k = 8*(l>>4)+e. B = W^T.
// ws (shorts): [0) W2f 65536 | [65536) W3f 16384 | [81920) W1f 8192
// f32 K-power table at byte 196608: kf[t*6400 + n*80 + k] = (K^t)[n][k]
// ---------------------------------------------------------------------------
__global__ __launch_bounds__(256) void prep_kernel(const float* __restrict__ W1,
                                                   const float* __restrict__ W2,
                                                   const float* __restrict__ W3,
                                                   short* __restrict__ ws) {
  int i = blockIdx.x * 256 + threadIdx.x;   // 0..65535
  {
    int e = i & 7, l = (i >> 3) & 63, nt = (i >> 9) & 15, kk = i >> 13;
    int g = nt * 16 + (l & 15);
    int h = kk * 32 + (l >> 4) * 8 + e;
    ws[i] = f2bf(W2[g * NH1 + h]);
  }
  if (i < 16384) {
    int e = i & 7, l = (i >> 3) & 63, nt = (i >> 9) & 3, kk = i >> 11;
    int g = nt * 16 + (l & 15);
    int h = kk * 32 + (l >> 4) * 8 + e;
    ws[65536 + i] = f2bf(W3[g * NH2 + h]);
  }
  if (i < 8192) {
    int e = i & 7, l = (i >> 3) & 63, nt = i >> 9;
    int g = nt * 16 + (l & 15);
    int k = (l >> 4) * 8 + e;
    ws[81920 + i] = (k < NDIM) ? f2bf(W1[g * NDIM + k]) : (short)0;
  }
}

// ---------------------------------------------------------------------------
// kpow: block bt computes K^(bt+1) via binary exponentiation with split-bf16
// MFMA. cur kept in LDS in BOTH orientations so A-frags (row-major rows) and
// B-frags (transposed rows) are contiguous float4 loads. 512 thr / 8 waves.
// LDS: kbuf 25600 | A0 | T0 | A1 | T1  = 128000 B.
// Named pointers + explicit swap (NO pointer arrays into LDS: backend
// rejects the addrspacecast initializer, and runtime-indexing would
// scratch-spill per rule #20).
// Writes f32 row-major K^t to kf[t*6400].
// ---------------------------------------------------------------------------
__global__ void kpow_kernel(const float* __restrict__ Kg, float* __restrict__ kf) {
  extern __shared__ char smem[];
  float* kbuf = (float*)smem;
  float* curA = (float*)(smem + 25600);
  float* curT = (float*)(smem + 51200);
  float* nxtA = (float*)(smem + 76800);
  float* nxtT = (float*)(smem + 102400);

  const int tid  = threadIdx.x;
  const int lane = tid & 63;
  const int w    = tid >> 6;
  const int m16  = lane & 15;
  const int kg   = lane >> 4;
  const int t    = blockIdx.x + 1;          // 1..63

  // init: kbuf = K, curA = K, curT = K^T
  for (int i = tid; i < 6400; i += 512) {
    float v = Kg[i];
    int r = i / 80, c = i - r * 80;
    kbuf[i] = v;
    curA[i] = v;
    curT[c * 80 + r] = v;
  }
  __syncthreads();

  // D = A * B (BT holds B^T); also writes D^T.
  auto mm = [&](const float* A, const float* BT, float* DA, float* DT) {
    for (int id = w; id < 25; id += 8) {
      const int mt = id / 5, nt = id % 5;
      f32x4 acc = {0.f, 0.f, 0.f, 0.f};
#pragma unroll
      for (int kk = 0; kk < 3; ++kk) {
        const bool valid = (kk < 2) || (kg < 2);
        bf16x8 ah, al, bh, bl;
        {
          float4 p0 = {0,0,0,0}, p1 = {0,0,0,0};
          if (valid) {
            const float* ap = A + (mt * 16 + m16) * 80 + kk * 32 + kg * 8;
            p0 = *(const float4*)ap; p1 = *(const float4*)(ap + 4);
          }
          split8(p0, p1, ah, al);
        }
        {
          float4 p0 = {0,0,0,0}, p1 = {0,0,0,0};
          if (valid) {
            const float* bp = BT + (nt * 16 + m16) * 80 + kk * 32 + kg * 8;
            p0 = *(const float4*)bp; p1 = *(const float4*)(bp + 4);
          }
          split8(p0, p1, bh, bl);
        }
        acc = MFMA(ah, bh, acc, 0, 0, 0);
        acc = MFMA(al, bh, acc, 0, 0, 0);
        acc = MFMA(ah, bl, acc, 0, 0, 0);
      }
      const int n = nt * 16 + m16;
      const int rowb = mt * 16 + kg * 4;
#pragma unroll
      for (int r = 0; r < 4; ++r) DA[(rowb + r) * 80 + n] = acc[r];
      *(float4*)(DT + n * 80 + rowb) = *(float4*)&acc;
    }
    __syncthreads();
  };

  const int h = 31 - __clz(t);
  for (int bit = h - 1; bit >= 0; --bit) {
    mm(curA, curT, nxtA, nxtT);                               // square
    { float* p;
      p = curA; curA = nxtA; nxtA = p;
      p = curT; curT = nxtT; nxtT = p; }
    if ((t >> bit) & 1) {
      mm(kbuf, curT, nxtA, nxtT);                             // K * cur
      { float* p;
        p = curA; curA = nxtA; nxtA = p;
        p = curT; curT = nxtT; nxtT = p; }
    }
  }

  // write K^t row-major (f32) to the table
  float4* dst = (float4*)(kf + t * 6400);
  const float4* src = (const float4*)curA;
  for (int i = tid; i < 1600; i += 512) dst[i] = src[i];
}

// ---------------------------------------------------------------------------
// MLP: one block = TWO batch rows (128 tokens), 512 threads = 8 waves.
// GEMM1/2: wave w -> M-half mh=w&1 (4 mtiles), N-quarter ng=w>>1 (4 ntiles).
// GEMM3:   wave w -> ntile w&3, mtiles (w>>2)*4..+3.
// B-frags direct from global (L2). y stored straight from registers (no ys).
// LDS: h1s [128][264] bf16 (67584 B); h2s overlays h1s. -> 2 blocks/CU.
// ---------------------------------------------------------------------------
__global__ __launch_bounds__(512, 4) void mlp_kernel(const float* __restrict__ x,
                                                     const float* __restrict__ b1g,
                                                     const float* __restrict__ b2g,
                                                     const short* __restrict__ ws,
                                                     float* __restrict__ y) {
  extern __shared__ char smem[];
  short* h1s = (short*)smem;            // [128][264]; h2 overlays after barrier

  const int tid  = threadIdx.x;
  const int lane = tid & 63;
  const int w    = tid >> 6;            // 0..7
  const int m16  = lane & 15;
  const int kg   = lane >> 4;
  const long b   = blockIdx.x;          // 2 batch rows each
  const int mh   = w & 1;
  const int ng   = w >> 1;

  const short* W2f = ws;
  const short* W3f = ws + 65536;
  const short* W1f = ws + 81920;

  const float4 xv = ((const float4*)(x + b * 2048))[tid];   // for y epilogue

  // ---- GEMM1: h1 = relu(x @ W1^T + b1); A-frags direct from global ----
  bf16x8 a1[4];
#pragma unroll
  for (int mt = 0; mt < 4; ++mt) {
    bf16x8 f = {};
    if (kg < 2) {
      const float4* xp =
          (const float4*)(x + (b * 128 + (mh * 4 + mt) * 16 + m16) * 16 + kg * 8);
      f = pack8(xp[0], xp[1]);
    }
    a1[mt] = f;
  }
#pragma unroll
  for (int nt = 0; nt < 4; ++nt) {
    const int n = ng * 4 + nt;
    const bf16x8 bb = *(const bf16x8*)(W1f + (n * 64 + lane) * 8);
    const float bias = b1g[n * 16 + m16];
#pragma unroll
    for (int mt = 0; mt < 4; ++mt) {
      f32x4 cc = {0.f, 0.f, 0.f, 0.f};
      cc = MFMA(a1[mt], bb, cc, 0, 0, 0);
      short* row = h1s + ((mh * 4 + mt) * 16 + kg * 4) * 264 + n * 16 + m16;
#pragma unroll
      for (int r = 0; r < 4; ++r) {
        float v = cc[r] + bias;
        v = v > 0.f ? v : 0.f;
        row[r * 264] = f2bf(v);
      }
    }
  }
  __syncthreads();

  // ---- GEMM2: h2 = relu(h1 @ W2^T + b2); K=256; 4mt x 4nt per wave ----
  f32x4 acc2[4][4];
#pragma unroll
  for (int mt = 0; mt < 4; ++mt)
#pragma unroll
    for (int nt = 0; nt < 4; ++nt) acc2[mt][nt] = (f32x4){0.f, 0.f, 0.f, 0.f};

  for (int kk = 0; kk < 8; ++kk) {
    bf16x8 bc[4];
#pragma unroll
    for (int nt = 0; nt < 4; ++nt)
      bc[nt] = *(const bf16x8*)(W2f + ((kk * 16 + ng * 4 + nt) * 64 + lane) * 8);
#pragma unroll
    for (int mt = 0; mt < 4; ++mt) {
      const bf16x8 a =
          *(const bf16x8*)(h1s + ((mh * 4 + mt) * 16 + m16) * 264 + kk * 32 + kg * 8);
#pragma unroll
      for (int nt = 0; nt < 4; ++nt)
        acc2[mt][nt] = MFMA(a, bc[nt], acc2[mt][nt], 0, 0, 0);
    }
  }
  __syncthreads();   // all h1 reads done -> overlay h2
  {
#pragma unroll
    for (int nt = 0; nt < 4; ++nt) {
      const int n = ng * 4 + nt;
      const float bias = b2g[n * 16 + m16];
#pragma unroll
      for (int mt = 0; mt < 4; ++mt) {
        short* row = h1s + ((mh * 4 + mt) * 16 + kg * 4) * 264 + n * 16 + m16;
#pragma unroll
        for (int r = 0; r < 4; ++r) {
          float v = acc2[mt][nt][r] + bias;
          v = v > 0.f ? v : 0.f;
          row[r * 264] = f2bf(v);
        }
      }
    }
  }
  __syncthreads();

  // ---- GEMM3: g = h2 @ W3^T; direct global stores of y ----
  const int nt3 = w & 3;
  const int mb  = (w >> 2) * 4;
  f32x4 acc3[4];
#pragma unroll
  for (int m = 0; m < 4; ++m) acc3[m] = (f32x4){0.f, 0.f, 0.f, 0.f};
  for (int kk = 0; kk < 8; ++kk) {
    const bf16x8 bb = *(const bf16x8*)(W3f + ((kk * 4 + nt3) * 64 + lane) * 8);
#pragma unroll
    for (int m = 0; m < 4; ++m) {
      const bf16x8 a =
          *(const bf16x8*)(h1s + ((mb + m) * 16 + m16) * 264 + kk * 32 + kg * 8);
      acc3[m] = MFMA(a, bb, acc3[m], 0, 0, 0);
    }
  }

  // y x-part: token = tid>>2, floats (tid&3)*4..+3 (exact f32 from regs)
  {
    float* yt = y + (b * 128 + (tid >> 2)) * 80 + (tid & 3) * 4;
    *(float4*)yt = xv;
  }
  // y g-part: 16 consecutive floats per (m,r) per 16-lane group
#pragma unroll
  for (int m = 0; m < 4; ++m)
#pragma unroll
    for (int r = 0; r < 4; ++r)
      y[(b * 128 + (mb + m) * 16 + kg * 4 + r) * 80 + 16 + nt3 * 16 + m16] =
          acc3[m][r];
}

// ---------------------------------------------------------------------------
// ypred: y_pred[b, t, :] = y0[b] @ (K^t)^T via split-bf16 MFMA.
// B-frags built on the fly from the f32 K^t table (B[k][n] = K^t[n][k], so
// row n of the row-major table is k-contiguous). grid = 16 batch-chunks x
// 32 t-groups (2 t each). 512 thr, wave w owns M-tiles {2w, 2w+1}.
// ---------------------------------------------------------------------------
__global__ __launch_bounds__(512, 4) void ypred_kernel(const float* __restrict__ kf,
                                                       const float* __restrict__ y,
                                                       float* __restrict__ yp) {
  const int tid  = threadIdx.x;
  const int lane = tid & 63;
  const int w    = tid >> 6;
  const int m16  = lane & 15;
  const int kg   = lane >> 4;
  const int bc   = blockIdx.x & 15;
  const int tg   = blockIdx.x >> 4;
  const long b0  = (long)bc * 256;

  // Build A hi/lo fragments from y0 (2 mt x 3 kk)
  bf16x8 ah[2][3], al[2][3];
#pragma unroll
  for (int m = 0; m < 2; ++m) {
#pragma unroll
    for (int kk = 0; kk < 3; ++kk) {
      const int k0 = kk * 32 + kg * 8;
      bf16x8 fh = {}, fl = {};
      if (k0 < 80) {
        const float4* p =
            (const float4*)(y + (b0 + (2 * w + m) * 16 + m16) * YROW + k0);
        split8(p[0], p[1], fh, fl);
      }
      ah[m][kk] = fh;
      al[m][kk] = fl;
    }
  }

  for (int tt = 0; tt < 2; ++tt) {
    const int t = tg * 2 + tt;
    if (t == 0) {
      for (int i = tid; i < 5120; i += 512) {
        int r = i / 20, q = (i % 20) * 4;
        *(float4*)(yp + (b0 + r) * YROW + q) = *(const float4*)(y + (b0 + r) * YROW + q);
      }
      continue;
    }
    const float* kt = kf + t * 6400;
    f32x4 acc[2][5];
#pragma unroll
    for (int m = 0; m < 2; ++m)
#pragma unroll
      for (int nt = 0; nt < 5; ++nt) acc[m][nt] = (f32x4){0.f, 0.f, 0.f, 0.f};

#pragma unroll
    for (int kk = 0; kk < 3; ++kk) {
      const bool valid = (kk < 2) || (kg < 2);
#pragma unroll
      for (int nt = 0; nt < 5; ++nt) {
        bf16x8 bh, bl;
        float4 q0 = {0,0,0,0}, q1 = {0,0,0,0};
        if (valid) {
          const float* bp = kt + (nt * 16 + m16) * 80 + kk * 32 + kg * 8;
          q0 = *(const float4*)bp; q1 = *(const float4*)(bp + 4);
        }
        split8(q0, q1, bh, bl);
#pragma unroll
        for (int m = 0; m < 2; ++m) {
          acc[m][nt] = MFMA(ah[m][kk], bh, acc[m][nt], 0, 0, 0);
          acc[m][nt] = MFMA(al[m][kk], bh, acc[m][nt], 0, 0, 0);
          acc[m][nt] = MFMA(ah[m][kk], bl, acc[m][nt], 0, 0, 0);
        }
      }
    }
#pragma unroll
    for (int m = 0; m < 2; ++m)
#pragma unroll
      for (int nt = 0; nt < 5; ++nt)
#pragma unroll
        for (int r = 0; r < 4; ++r)
          yp[(b0 + (2 * w + m) * 16 + kg * 4 + r) * YROW + (long)t * 80 + nt * 16 + m16] =
              acc[m][nt][r];
  }
}

extern "C" void kernel_launch(void* const* d_in, const int* in_sizes, int n_in,
                              void* d_out, int out_size, void* d_ws, size_t ws_size,
                              hipStream_t stream) {
  const float* x  = (const float*)d_in[0];
  const float* W1 = (const float*)d_in[1];
  const float* b1 = (const float*)d_in[2];
  const float* W2 = (const float*)d_in[3];
  const float* b2 = (const float*)d_in[4];
  const float* W3 = (const float*)d_in[5];
  const float* Kg = (const float*)d_in[6];
  float* y  = (float*)d_out;
  float* yp = y + (long)NB * YROW;
  short* ws = (short*)d_ws;
  float* kf = (float*)((char*)d_ws + 196608);   // f32 K-power table

  prep_kernel<<<256, 256, 0, stream>>>(W1, W2, W3, ws);
  kpow_kernel<<<63, 512, 128000, stream>>>(Kg, kf);
  mlp_kernel<<<NB / 2, 512, 67584, stream>>>(x, b1, b2, ws, y);
  ypred_kernel<<<512, 512, 0, stream>>>(kf, y, yp);
}

// Round 6
// 151.584 us; speedup vs baseline: 1.2304x; 1.0024x over previous
//
#include <hip/hip_runtime.h>
#include <hip/hip_bf16.h>

// Problem constants (hardcoded from setup_inputs; n_shifts == T == 64)
#define NB   4096
#define NT   64
#define NDIM 16
#define NH1  256
#define NH2  256
#define NLAT 64
#define NKD  80
#define YROW (NT * NKD)      // 5120 floats per batch row of y / y_pred
#define KTAB 98304           // short-offset of K-power fragment table in ws
#define KSLOT 15360          // shorts per t-slot (7680 hi + 7680 lo)

typedef __attribute__((ext_vector_type(8))) short bf16x8;
typedef __attribute__((ext_vector_type(4))) float f32x4;

#define MFMA __builtin_amdgcn_mfma_f32_16x16x32_bf16

static __device__ __forceinline__ short f2bf(float f) {
  union { float f; unsigned u; } v; v.f = f;
  unsigned r = v.u + 0x7fffu + ((v.u >> 16) & 1u);   // RNE
  return (short)(r >> 16);
}
static __device__ __forceinline__ float bf2f(short h) {
  union { unsigned u; float f; } v; v.u = ((unsigned)(unsigned short)h) << 16;
  return v.f;
}
static __device__ __forceinline__ bf16x8 pack8(float4 a, float4 b) {
  bf16x8 r;
  r[0] = f2bf(a.x); r[1] = f2bf(a.y); r[2] = f2bf(a.z); r[3] = f2bf(a.w);
  r[4] = f2bf(b.x); r[5] = f2bf(b.y); r[6] = f2bf(b.z); r[7] = f2bf(b.w);
  return r;
}
static __device__ __forceinline__ void split8(float4 v0, float4 v1, bf16x8& h, bf16x8& l) {
  h = pack8(v0, v1);
  float4 r0, r1;
  r0.x = v0.x - bf2f(h[0]); r0.y = v0.y - bf2f(h[1]);
  r0.z = v0.z - bf2f(h[2]); r0.w = v0.w - bf2f(h[3]);
  r1.x = v1.x - bf2f(h[4]); r1.y = v1.y - bf2f(h[5]);
  r1.z = v1.z - bf2f(h[6]); r1.w = v1.w - bf2f(h[7]);
  l = pack8(r0, r1);
}

// ---------------------------------------------------------------------------
// Prep: rearrange weights into MFMA fragment order (bf16) in workspace.
// Fragment: lane l holds W[g][k] with g = l&15, k = 8*(l>>4)+e. This serves
// BOTH as B-frag of W^T (old use) and as A-frag of W (new swapped use) —
// identical per-lane bytes.
// ws (shorts): [0) W2f 65536 | [65536) W3f 16384 | [81920) W1f 8192
// K-power hi/lo fragment table at short-offset KTAB (written by kpow).
// ---------------------------------------------------------------------------
__global__ __launch_bounds__(256) void prep_kernel(const float* __restrict__ W1,
                                                   const float* __restrict__ W2,
                                                   const float* __restrict__ W3,
                                                   short* __restrict__ ws) {
  int i = blockIdx.x * 256 + threadIdx.x;   // 0..65535
  {
    int e = i & 7, l = (i >> 3) & 63, nt = (i >> 9) & 15, kk = i >> 13;
    int g = nt * 16 + (l & 15);
    int h = kk * 32 + (l >> 4) * 8 + e;
    ws[i] = f2bf(W2[g * NH1 + h]);
  }
  if (i < 16384) {
    int e = i & 7, l = (i >> 3) & 63, nt = (i >> 9) & 3, kk = i >> 11;
    int g = nt * 16 + (l & 15);
    int h = kk * 32 + (l >> 4) * 8 + e;
    ws[65536 + i] = f2bf(W3[g * NH2 + h]);
  }
  if (i < 8192) {
    int e = i & 7, l = (i >> 3) & 63, nt = i >> 9;
    int g = nt * 16 + (l & 15);
    int k = (l >> 4) * 8 + e;
    ws[81920 + i] = (k < NDIM) ? f2bf(W1[g * NDIM + k]) : (short)0;
  }
}

// ---------------------------------------------------------------------------
// kpow: block bt computes K^(bt+1) via binary exponentiation with split-bf16
// MFMA (cur in LDS in both orientations; named pointers, explicit swap).
// Epilogue writes hi/lo split B-FRAGMENT table (ypred consumes directly):
// kt[idx] layout [kk3][nt5][lane64][e8], B[k][n] = (K^t)[n][k].
// ---------------------------------------------------------------------------
__global__ void kpow_kernel(const float* __restrict__ Kg, short* __restrict__ ws) {
  extern __shared__ char smem[];
  float* kbuf = (float*)smem;
  float* curA = (float*)(smem + 25600);
  float* curT = (float*)(smem + 51200);
  float* nxtA = (float*)(smem + 76800);
  float* nxtT = (float*)(smem + 102400);

  const int tid  = threadIdx.x;
  const int lane = tid & 63;
  const int w    = tid >> 6;
  const int m16  = lane & 15;
  const int kg   = lane >> 4;
  const int t    = blockIdx.x + 1;          // 1..63

  for (int i = tid; i < 6400; i += 512) {
    float v = Kg[i];
    int r = i / 80, c = i - r * 80;
    kbuf[i] = v;
    curA[i] = v;
    curT[c * 80 + r] = v;
  }
  __syncthreads();

  auto mm = [&](const float* A, const float* BT, float* DA, float* DT) {
    for (int id = w; id < 25; id += 8) {
      const int mt = id / 5, nt = id % 5;
      f32x4 acc = {0.f, 0.f, 0.f, 0.f};
#pragma unroll
      for (int kk = 0; kk < 3; ++kk) {
        const bool valid = (kk < 2) || (kg < 2);
        bf16x8 ah, al, bh, bl;
        {
          float4 p0 = {0,0,0,0}, p1 = {0,0,0,0};
          if (valid) {
            const float* ap = A + (mt * 16 + m16) * 80 + kk * 32 + kg * 8;
            p0 = *(const float4*)ap; p1 = *(const float4*)(ap + 4);
          }
          split8(p0, p1, ah, al);
        }
        {
          float4 p0 = {0,0,0,0}, p1 = {0,0,0,0};
          if (valid) {
            const float* bp = BT + (nt * 16 + m16) * 80 + kk * 32 + kg * 8;
            p0 = *(const float4*)bp; p1 = *(const float4*)(bp + 4);
          }
          split8(p0, p1, bh, bl);
        }
        acc = MFMA(ah, bh, acc, 0, 0, 0);
        acc = MFMA(al, bh, acc, 0, 0, 0);
        acc = MFMA(ah, bl, acc, 0, 0, 0);
      }
      const int n = nt * 16 + m16;
      const int rowb = mt * 16 + kg * 4;
#pragma unroll
      for (int r = 0; r < 4; ++r) DA[(rowb + r) * 80 + n] = acc[r];
      *(float4*)(DT + n * 80 + rowb) = *(float4*)&acc;
    }
    __syncthreads();
  };

  const int h = 31 - __clz(t);
  for (int bit = h - 1; bit >= 0; --bit) {
    mm(curA, curT, nxtA, nxtT);                               // square
    { float* p;
      p = curA; curA = nxtA; nxtA = p;
      p = curT; curT = nxtT; nxtT = p; }
    if ((t >> bit) & 1) {
      mm(kbuf, curT, nxtA, nxtT);                             // K * cur
      { float* p;
        p = curA; curA = nxtA; nxtA = p;
        p = curT; curT = nxtT; nxtT = p; }
    }
  }

  // write hi/lo split B-frag table: B[k][n] = (K^t)[n][k]
  short* kt = ws + KTAB + t * KSLOT;
  for (int idx = tid; idx < 7680; idx += 512) {
    int e = idx & 7, ln = (idx >> 3) & 63, rem = idx >> 9;   // rem = kk*5+nt
    int kk = rem / 5, nt = rem % 5;
    int k = kk * 32 + (ln >> 4) * 8 + e;
    int n = nt * 16 + (ln & 15);
    float v = (k < 80) ? curA[n * 80 + k] : 0.f;
    short hi = f2bf(v);
    kt[idx] = hi;
    kt[7680 + idx] = f2bf(v - bf2f(hi));
  }
}

// ---------------------------------------------------------------------------
// MLP (SWAPPED operands): one block = 2 batch rows (128 tokens), 8 waves.
// All GEMMs compute D = W_tile x act^T so D[out_unit][token]:
//   - A-frag = W fragment (from ws, as prep emits)
//   - B-frag = activation^T: per-lane bytes == row-major k-contig slice (free)
//   - D: col = token, rows = 4 consecutive out-units per lane
//     -> h-epilogues are ONE packed ds_write_b64 per tile (no scalar stores)
//     -> y g-part is ONE float4 global store per tile
//     -> bias is a float4 load (per-row bias)
// Wave split GEMM1/2: mg = w&3 (4 mtiles), ng = w>>2 (4 ntiles of tokens).
// GEMM3: mt3 = w&3 (1 mtile), nq = w>>2 (4 ntiles).
// LDS: h1s [128 tok][264] bf16 (67584 B); h2 overlays h1. 2 blocks/CU.
// 3 barriers total; GEMM1 reads x straight from global (no x staging).
// ---------------------------------------------------------------------------
__global__ __launch_bounds__(512, 4) void mlp_kernel(const float* __restrict__ x,
                                                     const float* __restrict__ b1g,
                                                     const float* __restrict__ b2g,
                                                     const short* __restrict__ ws,
                                                     float* __restrict__ y) {
  extern __shared__ char smem[];
  short* h1s = (short*)smem;            // [128][264]; h2 overlays after barrier

  const int tid  = threadIdx.x;
  const int lane = tid & 63;
  const int w    = tid >> 6;            // 0..7
  const int l15  = lane & 15;
  const int kg   = lane >> 4;
  const long b   = blockIdx.x;          // 2 batch rows each
  const int mg   = w & 3;
  const int ng   = w >> 2;

  const short* W2f = ws;
  const short* W3f = ws + 65536;
  const short* W1f = ws + 81920;

  const float4 xv = ((const float4*)(x + b * 2048))[tid];   // for y epilogue

  // ---- x B-frags (x^T): lane holds x[tok][k0..k0+7], tok = col ----
  bf16x8 xf[4];
#pragma unroll
  for (int j = 0; j < 4; ++j) {
    const int tok = (ng * 4 + j) * 16 + l15;
    bf16x8 f = {};
    if (kg < 2) {
      const float4* p = (const float4*)(x + (b * 128 + tok) * 16 + kg * 8);
      f = pack8(p[0], p[1]);
    }
    xf[j] = f;
  }

  // ---- GEMM1: D = W1 x x^T -> h1[tok][h] via packed b64 stores ----
#pragma unroll
  for (int i = 0; i < 4; ++i) {
    const int mt = mg * 4 + i;
    const bf16x8 wa = *(const bf16x8*)(W1f + (mt * 64 + lane) * 8);
    const float4 bias = *(const float4*)(b1g + mt * 16 + kg * 4);
#pragma unroll
    for (int j = 0; j < 4; ++j) {
      f32x4 c = {0.f, 0.f, 0.f, 0.f};
      c = MFMA(wa, xf[j], c, 0, 0, 0);
      const int tok = (ng * 4 + j) * 16 + l15;
      float v0 = c[0] + bias.x; v0 = v0 > 0.f ? v0 : 0.f;
      float v1 = c[1] + bias.y; v1 = v1 > 0.f ? v1 : 0.f;
      float v2 = c[2] + bias.z; v2 = v2 > 0.f ? v2 : 0.f;
      float v3 = c[3] + bias.w; v3 = v3 > 0.f ? v3 : 0.f;
      short4 st = {f2bf(v0), f2bf(v1), f2bf(v2), f2bf(v3)};
      *(short4*)(h1s + tok * 264 + mt * 16 + kg * 4) = st;
    }
  }
  __syncthreads();

  // ---- GEMM2: D = W2 x h1^T; K=256; acc 4mt x 4nt ----
  f32x4 acc2[4][4];
#pragma unroll
  for (int i = 0; i < 4; ++i)
#pragma unroll
    for (int j = 0; j < 4; ++j) acc2[i][j] = (f32x4){0.f, 0.f, 0.f, 0.f};

#pragma unroll 2
  for (int kk = 0; kk < 8; ++kk) {
    bf16x8 wa[4], hb[4];
#pragma unroll
    for (int i = 0; i < 4; ++i)
      wa[i] = *(const bf16x8*)(W2f + ((kk * 16 + mg * 4 + i) * 64 + lane) * 8);
#pragma unroll
    for (int j = 0; j < 4; ++j) {
      const int tok = (ng * 4 + j) * 16 + l15;
      hb[j] = *(const bf16x8*)(h1s + tok * 264 + kk * 32 + kg * 8);
    }
#pragma unroll
    for (int i = 0; i < 4; ++i)
#pragma unroll
      for (int j = 0; j < 4; ++j)
        acc2[i][j] = MFMA(wa[i], hb[j], acc2[i][j], 0, 0, 0);
  }
  __syncthreads();   // all h1 reads done -> overlay h2

#pragma unroll
  for (int i = 0; i < 4; ++i) {
    const int mt = mg * 4 + i;
    const float4 bias = *(const float4*)(b2g + mt * 16 + kg * 4);
#pragma unroll
    for (int j = 0; j < 4; ++j) {
      const int tok = (ng * 4 + j) * 16 + l15;
      float v0 = acc2[i][j][0] + bias.x; v0 = v0 > 0.f ? v0 : 0.f;
      float v1 = acc2[i][j][1] + bias.y; v1 = v1 > 0.f ? v1 : 0.f;
      float v2 = acc2[i][j][2] + bias.z; v2 = v2 > 0.f ? v2 : 0.f;
      float v3 = acc2[i][j][3] + bias.w; v3 = v3 > 0.f ? v3 : 0.f;
      short4 st = {f2bf(v0), f2bf(v1), f2bf(v2), f2bf(v3)};
      *(short4*)(h1s + tok * 264 + mt * 16 + kg * 4) = st;
    }
  }
  __syncthreads();

  // ---- GEMM3: D = W3 x h2^T; y stored straight from registers ----
  const int mt3 = w & 3;
  const int nq  = w >> 2;
  f32x4 acc3[4];
#pragma unroll
  for (int j = 0; j < 4; ++j) acc3[j] = (f32x4){0.f, 0.f, 0.f, 0.f};
#pragma unroll 2
  for (int kk = 0; kk < 8; ++kk) {
    const bf16x8 wa = *(const bf16x8*)(W3f + ((kk * 4 + mt3) * 64 + lane) * 8);
#pragma unroll
    for (int j = 0; j < 4; ++j) {
      const int tok = (nq * 4 + j) * 16 + l15;
      const bf16x8 hb = *(const bf16x8*)(h1s + tok * 264 + kk * 32 + kg * 8);
      acc3[j] = MFMA(wa, hb, acc3[j], 0, 0, 0);
    }
  }

  // y x-part: token = tid>>2, floats (tid&3)*4..+3 (exact f32 from regs)
  *(float4*)(y + (b * 128 + (tid >> 2)) * 80 + (tid & 3) * 4) = xv;
  // y g-part: one float4 per tile (4 consecutive lat units of one token)
#pragma unroll
  for (int j = 0; j < 4; ++j) {
    const int tok = (nq * 4 + j) * 16 + l15;
    *(float4*)(y + (b * 128 + tok) * 80 + 16 + mt3 * 16 + kg * 4) =
        *(float4*)&acc3[j];
  }
}

// ---------------------------------------------------------------------------
// ypred: y_pred[b, t, :] = y0[b] @ (K^t)^T via split-bf16 MFMA; B-frags read
// DIRECTLY from the precomputed hi/lo table (no on-the-fly split).
// grid = 16 batch-chunks x 32 t-groups (2 t each). Wave w: M-tiles {2w,2w+1}.
// ---------------------------------------------------------------------------
__global__ __launch_bounds__(512, 4) void ypred_kernel(const short* __restrict__ ws,
                                                       const float* __restrict__ y,
                                                       float* __restrict__ yp) {
  const int tid  = threadIdx.x;
  const int lane = tid & 63;
  const int w    = tid >> 6;
  const int m16  = lane & 15;
  const int kg   = lane >> 4;
  const int bc   = blockIdx.x & 15;
  const int tg   = blockIdx.x >> 4;
  const long b0  = (long)bc * 256;

  // Build A hi/lo fragments from y0 (2 mt x 3 kk)
  bf16x8 ah[2][3], al[2][3];
#pragma unroll
  for (int m = 0; m < 2; ++m) {
#pragma unroll
    for (int kk = 0; kk < 3; ++kk) {
      const int k0 = kk * 32 + kg * 8;
      bf16x8 fh = {}, fl = {};
      if (k0 < 80) {
        const float4* p =
            (const float4*)(y + (b0 + (2 * w + m) * 16 + m16) * YROW + k0);
        split8(p[0], p[1], fh, fl);
      }
      ah[m][kk] = fh;
      al[m][kk] = fl;
    }
  }

  for (int tt = 0; tt < 2; ++tt) {
    const int t = tg * 2 + tt;
    if (t == 0) {
      for (int i = tid; i < 5120; i += 512) {
        int r = i / 20, q = (i % 20) * 4;
        *(float4*)(yp + (b0 + r) * YROW + q) = *(const float4*)(y + (b0 + r) * YROW + q);
      }
      continue;
    }
    const short* kt = ws + KTAB + t * KSLOT;
    f32x4 acc[2][5];
#pragma unroll
    for (int m = 0; m < 2; ++m)
#pragma unroll
      for (int nt = 0; nt < 5; ++nt) acc[m][nt] = (f32x4){0.f, 0.f, 0.f, 0.f};

#pragma unroll
    for (int kk = 0; kk < 3; ++kk) {
#pragma unroll
      for (int nt = 0; nt < 5; ++nt) {
        const bf16x8 bh = *(const bf16x8*)(kt + ((kk * 5 + nt) * 64 + lane) * 8);
        const bf16x8 bl = *(const bf16x8*)(kt + 7680 + ((kk * 5 + nt) * 64 + lane) * 8);
#pragma unroll
        for (int m = 0; m < 2; ++m) {
          acc[m][nt] = MFMA(ah[m][kk], bh, acc[m][nt], 0, 0, 0);
          acc[m][nt] = MFMA(al[m][kk], bh, acc[m][nt], 0, 0, 0);
          acc[m][nt] = MFMA(ah[m][kk], bl, acc[m][nt], 0, 0, 0);
        }
      }
    }
#pragma unroll
    for (int m = 0; m < 2; ++m)
#pragma unroll
      for (int nt = 0; nt < 5; ++nt)
#pragma unroll
        for (int r = 0; r < 4; ++r)
          yp[(b0 + (2 * w + m) * 16 + kg * 4 + r) * YROW + (long)t * 80 + nt * 16 + m16] =
              acc[m][nt][r];
  }
}

extern "C" void kernel_launch(void* const* d_in, const int* in_sizes, int n_in,
                              void* d_out, int out_size, void* d_ws, size_t ws_size,
                              hipStream_t stream) {
  const float* x  = (const float*)d_in[0];
  const float* W1 = (const float*)d_in[1];
  const float* b1 = (const float*)d_in[2];
  const float* W2 = (const float*)d_in[3];
  const float* b2 = (const float*)d_in[4];
  const float* W3 = (const float*)d_in[5];
  const float* Kg = (const float*)d_in[6];
  float* y  = (float*)d_out;
  float* yp = y + (long)NB * YROW;
  short* ws = (short*)d_ws;

  prep_kernel<<<256, 256, 0, stream>>>(W1, W2, W3, ws);
  kpow_kernel<<<63, 512, 128000, stream>>>(Kg, ws);
  mlp_kernel<<<NB / 2, 512, 67584, stream>>>(x, b1, b2, ws, y);
  ypred_kernel<<<512, 512, 0, stream>>>(ws, y, yp);
}

// Round 7
// 118.726 us; speedup vs baseline: 1.5709x; 1.2768x over previous
//
#include <hip/hip_runtime.h>
#include <hip/hip_bf16.h>

// Problem constants (hardcoded from setup_inputs; n_shifts == T == 64)
#define NB   4096
#define NT   64
#define NDIM 16
#define NH1  256
#define NH2  256
#define NLAT 64
#define NKD  80
#define YROW (NT * NKD)      // 5120 floats per batch row of y / y_pred
#define KTAB 98304           // short-offset of K-power fragment table in ws
#define KSLOT 15360          // shorts per t-slot (7680 hi + 7680 lo)

// kpow frag-image geometry: hi at [row][0..79], lo at [row][96..175]
#define FROW 184             // shorts/row: 368 B = 16B-aligned, 92-dword
                             // stride -> 2-way bank aliasing (free, m136)
#define FIMG_B (80 * FROW * 2)   // 29440 bytes per image

typedef __attribute__((ext_vector_type(8))) short bf16x8;
typedef __attribute__((ext_vector_type(4))) float f32x4;

#define MFMA __builtin_amdgcn_mfma_f32_16x16x32_bf16

static __device__ __forceinline__ short f2bf(float f) {
  union { float f; unsigned u; } v; v.f = f;
  unsigned r = v.u + 0x7fffu + ((v.u >> 16) & 1u);   // RNE
  return (short)(r >> 16);
}
static __device__ __forceinline__ float bf2f(short h) {
  union { unsigned u; float f; } v; v.u = ((unsigned)(unsigned short)h) << 16;
  return v.f;
}
static __device__ __forceinline__ bf16x8 pack8(float4 a, float4 b) {
  bf16x8 r;
  r[0] = f2bf(a.x); r[1] = f2bf(a.y); r[2] = f2bf(a.z); r[3] = f2bf(a.w);
  r[4] = f2bf(b.x); r[5] = f2bf(b.y); r[6] = f2bf(b.z); r[7] = f2bf(b.w);
  return r;
}
static __device__ __forceinline__ void split8(float4 v0, float4 v1, bf16x8& h, bf16x8& l) {
  h = pack8(v0, v1);
  float4 r0, r1;
  r0.x = v0.x - bf2f(h[0]); r0.y = v0.y - bf2f(h[1]);
  r0.z = v0.z - bf2f(h[2]); r0.w = v0.w - bf2f(h[3]);
  r1.x = v1.x - bf2f(h[4]); r1.y = v1.y - bf2f(h[5]);
  r1.z = v1.z - bf2f(h[6]); r1.w = v1.w - bf2f(h[7]);
  l = pack8(r0, r1);
}

// ---------------------------------------------------------------------------
// Prep: rearrange weights into MFMA fragment order (bf16) in workspace.
// Fragment: lane l holds W[g][k] with g = l&15, k = 8*(l>>4)+e.
// ws (shorts): [0) W2f 65536 | [65536) W3f 16384 | [81920) W1f 8192
// K-power hi/lo fragment table at short-offset KTAB (written by kpow).
// ---------------------------------------------------------------------------
__global__ __launch_bounds__(256) void prep_kernel(const float* __restrict__ W1,
                                                   const float* __restrict__ W2,
                                                   const float* __restrict__ W3,
                                                   short* __restrict__ ws) {
  int i = blockIdx.x * 256 + threadIdx.x;   // 0..65535
  {
    int e = i & 7, l = (i >> 3) & 63, nt = (i >> 9) & 15, kk = i >> 13;
    int g = nt * 16 + (l & 15);
    int h = kk * 32 + (l >> 4) * 8 + e;
    ws[i] = f2bf(W2[g * NH1 + h]);
  }
  if (i < 16384) {
    int e = i & 7, l = (i >> 3) & 63, nt = (i >> 9) & 3, kk = i >> 11;
    int g = nt * 16 + (l & 15);
    int h = kk * 32 + (l >> 4) * 8 + e;
    ws[65536 + i] = f2bf(W3[g * NH2 + h]);
  }
  if (i < 8192) {
    int e = i & 7, l = (i >> 3) & 63, nt = i >> 9;
    int g = nt * 16 + (l & 15);
    int k = (l >> 4) * 8 + e;
    ws[81920 + i] = (k < NDIM) ? f2bf(W1[g * NDIM + k]) : (short)0;
  }
}

// ---------------------------------------------------------------------------
// kpow v3: block bt computes K^(bt+1) via binary exponentiation.
// The running power M lives in LDS as PRE-SPLIT hi/lo bf16 frag images in
// BOTH orientations (Aimg[r][k]=M[r][k]; Bimg[n][k]=M[k][n]), so the mm
// inner loop is pure {ds_read_b128 x4 -> 3 MFMA} with ZERO split VALU.
// The split happens once per output element in the epilogue.
// LDS: kA | curA | curB | nxtA | nxtB = 5 x 29440 = 147200 B (1 block/CU).
// Epilogue writes the hi/lo B-frag table for ypred straight from curA.
// ---------------------------------------------------------------------------
__global__ void kpow_kernel(const float* __restrict__ Kg, short* __restrict__ ws) {
  extern __shared__ char smem[];
  short* kA   = (short*)smem;                       // K, A-orientation
  short* curA = (short*)(smem + FIMG_B);
  short* curB = (short*)(smem + 2 * FIMG_B);
  short* nxtA = (short*)(smem + 3 * FIMG_B);
  short* nxtB = (short*)(smem + 4 * FIMG_B);

  const int tid  = threadIdx.x;
  const int lane = tid & 63;
  const int w    = tid >> 6;
  const int l15  = lane & 15;
  const int kg   = lane >> 4;
  const int t    = blockIdx.x + 1;          // 1..63

  // init images from K: Aimg[r][c] = K[r][c]; Bimg[c][r] = K[r][c]
  for (int i = tid; i < 6400; i += 512) {
    float v = Kg[i];
    int r = i / 80, c = i - r * 80;
    short hi = f2bf(v);
    short lo = f2bf(v - bf2f(hi));
    kA[r * FROW + c] = hi;        kA[r * FROW + 96 + c] = lo;
    curA[r * FROW + c] = hi;      curA[r * FROW + 96 + c] = lo;
    curB[c * FROW + r] = hi;      curB[c * FROW + 96 + r] = lo;
  }
  __syncthreads();

  // D = A*B from frag images; writes D in both orientations (split once).
  auto mm = [&](const short* Ai, const short* Bi, short* DA, short* DB) {
    for (int id = w; id < 25; id += 8) {
      const int mt = id / 5, nt = id % 5;
      f32x4 acc = {0.f, 0.f, 0.f, 0.f};
#pragma unroll
      for (int kk = 0; kk < 3; ++kk) {
        const int k0 = kk * 32 + kg * 8;
        bf16x8 ah = {}, al = {}, bh = {}, bl = {};
        if (k0 < 80) {
          const short* ap = Ai + (mt * 16 + l15) * FROW + k0;
          const short* bp = Bi + (nt * 16 + l15) * FROW + k0;
          ah = *(const bf16x8*)ap;  al = *(const bf16x8*)(ap + 96);
          bh = *(const bf16x8*)bp;  bl = *(const bf16x8*)(bp + 96);
        }
        acc = MFMA(ah, bh, acc, 0, 0, 0);
        acc = MFMA(al, bh, acc, 0, 0, 0);
        acc = MFMA(ah, bl, acc, 0, 0, 0);
      }
      const int n = nt * 16 + l15;
      const int rowb = mt * 16 + kg * 4;
      short4 hs, ls;
#pragma unroll
      for (int r = 0; r < 4; ++r) {
        float v = acc[r];
        short hi = f2bf(v);
        short lo = f2bf(v - bf2f(hi));
        DA[(rowb + r) * FROW + n] = hi;
        DA[(rowb + r) * FROW + 96 + n] = lo;
        ((short*)&hs)[r] = hi;
        ((short*)&ls)[r] = lo;
      }
      *(short4*)(DB + n * FROW + rowb) = hs;
      *(short4*)(DB + n * FROW + 96 + rowb) = ls;
    }
    __syncthreads();
  };

  const int h = 31 - __clz(t);
  for (int bit = h - 1; bit >= 0; --bit) {
    mm(curA, curB, nxtA, nxtB);                               // square
    { short* p;
      p = curA; curA = nxtA; nxtA = p;
      p = curB; curB = nxtB; nxtB = p; }
    if ((t >> bit) & 1) {
      mm(kA, curB, nxtA, nxtB);                               // K * cur
      { short* p;
        p = curA; curA = nxtA; nxtA = p;
        p = curB; curB = nxtB; nxtB = p; }
    }
  }

  // hi/lo B-frag table for ypred: B[k][n] = (K^t)[n][k] = Aimg[n][k]
  short* kt = ws + KTAB + t * KSLOT;
  for (int s = tid; s < 960; s += 512) {
    int f = s >> 6, ln = s & 63;            // f = kk*5 + nt
    int kk = f / 5, nt = f % 5;
    int k0 = kk * 32 + (ln >> 4) * 8;
    int n  = nt * 16 + (ln & 15);
    bf16x8 h8 = {}, l8 = {};
    if (k0 < 80) {
      const short* ap = curA + n * FROW + k0;
      h8 = *(const bf16x8*)ap;
      l8 = *(const bf16x8*)(ap + 96);
    }
    *(bf16x8*)(kt + f * 512 + ln * 8) = h8;
    *(bf16x8*)(kt + 7680 + f * 512 + ln * 8) = l8;
  }
}

// ---------------------------------------------------------------------------
// MLP (unchanged from round 6): one block = 2 batch rows (128 tokens),
// 8 waves, swapped operands D = W x act^T; h in LDS [128][264] (2-way bank
// aliasing = free); 2 blocks/CU. ~570 TF effective (structure-bound).
// ---------------------------------------------------------------------------
__global__ __launch_bounds__(512, 4) void mlp_kernel(const float* __restrict__ x,
                                                     const float* __restrict__ b1g,
                                                     const float* __restrict__ b2g,
                                                     const short* __restrict__ ws,
                                                     float* __restrict__ y) {
  extern __shared__ char smem[];
  short* h1s = (short*)smem;            // [128][264]; h2 overlays after barrier

  const int tid  = threadIdx.x;
  const int lane = tid & 63;
  const int w    = tid >> 6;            // 0..7
  const int l15  = lane & 15;
  const int kg   = lane >> 4;
  const long b   = blockIdx.x;          // 2 batch rows each
  const int mg   = w & 3;
  const int ng   = w >> 2;

  const short* W2f = ws;
  const short* W3f = ws + 65536;
  const short* W1f = ws + 81920;

  const float4 xv = ((const float4*)(x + b * 2048))[tid];   // for y epilogue

  // ---- x B-frags (x^T): lane holds x[tok][k0..k0+7], tok = col ----
  bf16x8 xf[4];
#pragma unroll
  for (int j = 0; j < 4; ++j) {
    const int tok = (ng * 4 + j) * 16 + l15;
    bf16x8 f = {};
    if (kg < 2) {
      const float4* p = (const float4*)(x + (b * 128 + tok) * 16 + kg * 8);
      f = pack8(p[0], p[1]);
    }
    xf[j] = f;
  }

  // ---- GEMM1: D = W1 x x^T -> h1[tok][h] via packed b64 stores ----
#pragma unroll
  for (int i = 0; i < 4; ++i) {
    const int mt = mg * 4 + i;
    const bf16x8 wa = *(const bf16x8*)(W1f + (mt * 64 + lane) * 8);
    const float4 bias = *(const float4*)(b1g + mt * 16 + kg * 4);
#pragma unroll
    for (int j = 0; j < 4; ++j) {
      f32x4 c = {0.f, 0.f, 0.f, 0.f};
      c = MFMA(wa, xf[j], c, 0, 0, 0);
      const int tok = (ng * 4 + j) * 16 + l15;
      float v0 = c[0] + bias.x; v0 = v0 > 0.f ? v0 : 0.f;
      float v1 = c[1] + bias.y; v1 = v1 > 0.f ? v1 : 0.f;
      float v2 = c[2] + bias.z; v2 = v2 > 0.f ? v2 : 0.f;
      float v3 = c[3] + bias.w; v3 = v3 > 0.f ? v3 : 0.f;
      short4 st = {f2bf(v0), f2bf(v1), f2bf(v2), f2bf(v3)};
      *(short4*)(h1s + tok * 264 + mt * 16 + kg * 4) = st;
    }
  }
  __syncthreads();

  // ---- GEMM2: D = W2 x h1^T; K=256; acc 4mt x 4nt ----
  f32x4 acc2[4][4];
#pragma unroll
  for (int i = 0; i < 4; ++i)
#pragma unroll
    for (int j = 0; j < 4; ++j) acc2[i][j] = (f32x4){0.f, 0.f, 0.f, 0.f};

#pragma unroll 2
  for (int kk = 0; kk < 8; ++kk) {
    bf16x8 wa[4], hb[4];
#pragma unroll
    for (int i = 0; i < 4; ++i)
      wa[i] = *(const bf16x8*)(W2f + ((kk * 16 + mg * 4 + i) * 64 + lane) * 8);
#pragma unroll
    for (int j = 0; j < 4; ++j) {
      const int tok = (ng * 4 + j) * 16 + l15;
      hb[j] = *(const bf16x8*)(h1s + tok * 264 + kk * 32 + kg * 8);
    }
#pragma unroll
    for (int i = 0; i < 4; ++i)
#pragma unroll
      for (int j = 0; j < 4; ++j)
        acc2[i][j] = MFMA(wa[i], hb[j], acc2[i][j], 0, 0, 0);
  }
  __syncthreads();   // all h1 reads done -> overlay h2

#pragma unroll
  for (int i = 0; i < 4; ++i) {
    const int mt = mg * 4 + i;
    const float4 bias = *(const float4*)(b2g + mt * 16 + kg * 4);
#pragma unroll
    for (int j = 0; j < 4; ++j) {
      const int tok = (ng * 4 + j) * 16 + l15;
      float v0 = acc2[i][j][0] + bias.x; v0 = v0 > 0.f ? v0 : 0.f;
      float v1 = acc2[i][j][1] + bias.y; v1 = v1 > 0.f ? v1 : 0.f;
      float v2 = acc2[i][j][2] + bias.z; v2 = v2 > 0.f ? v2 : 0.f;
      float v3 = acc2[i][j][3] + bias.w; v3 = v3 > 0.f ? v3 : 0.f;
      short4 st = {f2bf(v0), f2bf(v1), f2bf(v2), f2bf(v3)};
      *(short4*)(h1s + tok * 264 + mt * 16 + kg * 4) = st;
    }
  }
  __syncthreads();

  // ---- GEMM3: D = W3 x h2^T; y stored straight from registers ----
  const int mt3 = w & 3;
  const int nq  = w >> 2;
  f32x4 acc3[4];
#pragma unroll
  for (int j = 0; j < 4; ++j) acc3[j] = (f32x4){0.f, 0.f, 0.f, 0.f};
#pragma unroll 2
  for (int kk = 0; kk < 8; ++kk) {
    const bf16x8 wa = *(const bf16x8*)(W3f + ((kk * 4 + mt3) * 64 + lane) * 8);
#pragma unroll
    for (int j = 0; j < 4; ++j) {
      const int tok = (nq * 4 + j) * 16 + l15;
      const bf16x8 hb = *(const bf16x8*)(h1s + tok * 264 + kk * 32 + kg * 8);
      acc3[j] = MFMA(wa, hb, acc3[j], 0, 0, 0);
    }
  }

  // y x-part: token = tid>>2, floats (tid&3)*4..+3 (exact f32 from regs)
  *(float4*)(y + (b * 128 + (tid >> 2)) * 80 + (tid & 3) * 4) = xv;
  // y g-part: one float4 per tile (4 consecutive lat units of one token)
#pragma unroll
  for (int j = 0; j < 4; ++j) {
    const int tok = (nq * 4 + j) * 16 + l15;
    *(float4*)(y + (b * 128 + tok) * 80 + 16 + mt3 * 16 + kg * 4) =
        *(float4*)&acc3[j];
  }
}

// ---------------------------------------------------------------------------
// ypred (unchanged): y_pred[b, t, :] = y0[b] @ (K^t)^T via split-bf16 MFMA;
// B-frags read directly from the precomputed hi/lo table.
// grid = 16 batch-chunks x 32 t-groups (2 t each). Wave w: M-tiles {2w,2w+1}.
// ---------------------------------------------------------------------------
__global__ __launch_bounds__(512, 4) void ypred_kernel(const short* __restrict__ ws,
                                                       const float* __restrict__ y,
                                                       float* __restrict__ yp) {
  const int tid  = threadIdx.x;
  const int lane = tid & 63;
  const int w    = tid >> 6;
  const int m16  = lane & 15;
  const int kg   = lane >> 4;
  const int bc   = blockIdx.x & 15;
  const int tg   = blockIdx.x >> 4;
  const long b0  = (long)bc * 256;

  // Build A hi/lo fragments from y0 (2 mt x 3 kk)
  bf16x8 ah[2][3], al[2][3];
#pragma unroll
  for (int m = 0; m < 2; ++m) {
#pragma unroll
    for (int kk = 0; kk < 3; ++kk) {
      const int k0 = kk * 32 + kg * 8;
      bf16x8 fh = {}, fl = {};
      if (k0 < 80) {
        const float4* p =
            (const float4*)(y + (b0 + (2 * w + m) * 16 + m16) * YROW + k0);
        split8(p[0], p[1], fh, fl);
      }
      ah[m][kk] = fh;
      al[m][kk] = fl;
    }
  }

  for (int tt = 0; tt < 2; ++tt) {
    const int t = tg * 2 + tt;
    if (t == 0) {
      for (int i = tid; i < 5120; i += 512) {
        int r = i / 20, q = (i % 20) * 4;
        *(float4*)(yp + (b0 + r) * YROW + q) = *(const float4*)(y + (b0 + r) * YROW + q);
      }
      continue;
    }
    const short* kt = ws + KTAB + t * KSLOT;
    f32x4 acc[2][5];
#pragma unroll
    for (int m = 0; m < 2; ++m)
#pragma unroll
      for (int nt = 0; nt < 5; ++nt) acc[m][nt] = (f32x4){0.f, 0.f, 0.f, 0.f};

#pragma unroll
    for (int kk = 0; kk < 3; ++kk) {
#pragma unroll
      for (int nt = 0; nt < 5; ++nt) {
        const bf16x8 bh = *(const bf16x8*)(kt + ((kk * 5 + nt) * 64 + lane) * 8);
        const bf16x8 bl = *(const bf16x8*)(kt + 7680 + ((kk * 5 + nt) * 64 + lane) * 8);
#pragma unroll
        for (int m = 0; m < 2; ++m) {
          acc[m][nt] = MFMA(ah[m][kk], bh, acc[m][nt], 0, 0, 0);
          acc[m][nt] = MFMA(al[m][kk], bh, acc[m][nt], 0, 0, 0);
          acc[m][nt] = MFMA(ah[m][kk], bl, acc[m][nt], 0, 0, 0);
        }
      }
    }
#pragma unroll
    for (int m = 0; m < 2; ++m)
#pragma unroll
      for (int nt = 0; nt < 5; ++nt)
#pragma unroll
        for (int r = 0; r < 4; ++r)
          yp[(b0 + (2 * w + m) * 16 + kg * 4 + r) * YROW + (long)t * 80 + nt * 16 + m16] =
              acc[m][nt][r];
  }
}

extern "C" void kernel_launch(void* const* d_in, const int* in_sizes, int n_in,
                              void* d_out, int out_size, void* d_ws, size_t ws_size,
                              hipStream_t stream) {
  const float* x  = (const float*)d_in[0];
  const float* W1 = (const float*)d_in[1];
  const float* b1 = (const float*)d_in[2];
  const float* W2 = (const float*)d_in[3];
  const float* b2 = (const float*)d_in[4];
  const float* W3 = (const float*)d_in[5];
  const float* Kg = (const float*)d_in[6];
  float* y  = (float*)d_out;
  float* yp = y + (long)NB * YROW;
  short* ws = (short*)d_ws;

  prep_kernel<<<256, 256, 0, stream>>>(W1, W2, W3, ws);
  kpow_kernel<<<63, 512, 5 * FIMG_B, stream>>>(Kg, ws);
  mlp_kernel<<<NB / 2, 512, 67584, stream>>>(x, b1, b2, ws, y);
  ypred_kernel<<<512, 512, 0, stream>>>(ws, y, yp);
}

// Round 8
// 118.691 us; speedup vs baseline: 1.5713x; 1.0003x over previous
//
#include <hip/hip_runtime.h>
#include <hip/hip_bf16.h>

// Problem constants (hardcoded from setup_inputs; n_shifts == T == 64)
#define NB   4096
#define NT   64
#define NDIM 16
#define NH1  256
#define NH2  256
#define NLAT 64
#define NKD  80
#define YROW (NT * NKD)      // 5120 floats per batch row of y / y_pred
#define KTAB 98304           // short-offset of K-power fragment table in ws
#define KSLOT 15360          // shorts per t-slot (7680 hi + 7680 lo)

// kpow frag-image geometry: hi at [row][0..79], lo at [row][96..175]
#define FROW 184             // shorts/row: 368 B = 16B-aligned, 92-dword
                             // stride -> 2-way bank aliasing (free, m136)
#define FIMG_B (80 * FROW * 2)   // 29440 bytes per image

typedef __attribute__((ext_vector_type(8))) short bf16x8;
typedef __attribute__((ext_vector_type(4))) float f32x4;

#define MFMA __builtin_amdgcn_mfma_f32_16x16x32_bf16

static __device__ __forceinline__ short f2bf(float f) {
  union { float f; unsigned u; } v; v.f = f;
  unsigned r = v.u + 0x7fffu + ((v.u >> 16) & 1u);   // RNE
  return (short)(r >> 16);
}
static __device__ __forceinline__ float bf2f(short h) {
  union { unsigned u; float f; } v; v.u = ((unsigned)(unsigned short)h) << 16;
  return v.f;
}
static __device__ __forceinline__ bf16x8 pack8(float4 a, float4 b) {
  bf16x8 r;
  r[0] = f2bf(a.x); r[1] = f2bf(a.y); r[2] = f2bf(a.z); r[3] = f2bf(a.w);
  r[4] = f2bf(b.x); r[5] = f2bf(b.y); r[6] = f2bf(b.z); r[7] = f2bf(b.w);
  return r;
}
static __device__ __forceinline__ void split8(float4 v0, float4 v1, bf16x8& h, bf16x8& l) {
  h = pack8(v0, v1);
  float4 r0, r1;
  r0.x = v0.x - bf2f(h[0]); r0.y = v0.y - bf2f(h[1]);
  r0.z = v0.z - bf2f(h[2]); r0.w = v0.w - bf2f(h[3]);
  r1.x = v1.x - bf2f(h[4]); r1.y = v1.y - bf2f(h[5]);
  r1.z = v1.z - bf2f(h[6]); r1.w = v1.w - bf2f(h[7]);
  l = pack8(r0, r1);
}

// ---------------------------------------------------------------------------
// Prep: rearrange weights into MFMA fragment order (bf16) in workspace.
// Fragment: lane l holds W[g][k] with g = l&15, k = 8*(l>>4)+e.
// ws (shorts): [0) W2f 65536 | [65536) W3f 16384 | [81920) W1f 8192
// K-power hi/lo fragment table at short-offset KTAB (written by kpow).
// ---------------------------------------------------------------------------
__global__ __launch_bounds__(256) void prep_kernel(const float* __restrict__ W1,
                                                   const float* __restrict__ W2,
                                                   const float* __restrict__ W3,
                                                   short* __restrict__ ws) {
  int i = blockIdx.x * 256 + threadIdx.x;   // 0..65535
  {
    int e = i & 7, l = (i >> 3) & 63, nt = (i >> 9) & 15, kk = i >> 13;
    int g = nt * 16 + (l & 15);
    int h = kk * 32 + (l >> 4) * 8 + e;
    ws[i] = f2bf(W2[g * NH1 + h]);
  }
  if (i < 16384) {
    int e = i & 7, l = (i >> 3) & 63, nt = (i >> 9) & 3, kk = i >> 11;
    int g = nt * 16 + (l & 15);
    int h = kk * 32 + (l >> 4) * 8 + e;
    ws[65536 + i] = f2bf(W3[g * NH2 + h]);
  }
  if (i < 8192) {
    int e = i & 7, l = (i >> 3) & 63, nt = i >> 9;
    int g = nt * 16 + (l & 15);
    int k = (l >> 4) * 8 + e;
    ws[81920 + i] = (k < NDIM) ? f2bf(W1[g * NDIM + k]) : (short)0;
  }
}

// ---------------------------------------------------------------------------
// kpow v3 (unchanged, proven ~5 us): binary exponentiation with the running
// power kept as PRE-SPLIT hi/lo bf16 frag images in both orientations.
// mm inner loop = pure {ds_read_b128 x4 -> 3 MFMA}, zero split VALU.
// ---------------------------------------------------------------------------
__global__ void kpow_kernel(const float* __restrict__ Kg, short* __restrict__ ws) {
  extern __shared__ char smem[];
  short* kA   = (short*)smem;                       // K, A-orientation
  short* curA = (short*)(smem + FIMG_B);
  short* curB = (short*)(smem + 2 * FIMG_B);
  short* nxtA = (short*)(smem + 3 * FIMG_B);
  short* nxtB = (short*)(smem + 4 * FIMG_B);

  const int tid  = threadIdx.x;
  const int lane = tid & 63;
  const int w    = tid >> 6;
  const int l15  = lane & 15;
  const int kg   = lane >> 4;
  const int t    = blockIdx.x + 1;          // 1..63

  for (int i = tid; i < 6400; i += 512) {
    float v = Kg[i];
    int r = i / 80, c = i - r * 80;
    short hi = f2bf(v);
    short lo = f2bf(v - bf2f(hi));
    kA[r * FROW + c] = hi;        kA[r * FROW + 96 + c] = lo;
    curA[r * FROW + c] = hi;      curA[r * FROW + 96 + c] = lo;
    curB[c * FROW + r] = hi;      curB[c * FROW + 96 + r] = lo;
  }
  __syncthreads();

  auto mm = [&](const short* Ai, const short* Bi, short* DA, short* DB) {
    for (int id = w; id < 25; id += 8) {
      const int mt = id / 5, nt = id % 5;
      f32x4 acc = {0.f, 0.f, 0.f, 0.f};
#pragma unroll
      for (int kk = 0; kk < 3; ++kk) {
        const int k0 = kk * 32 + kg * 8;
        bf16x8 ah = {}, al = {}, bh = {}, bl = {};
        if (k0 < 80) {
          const short* ap = Ai + (mt * 16 + l15) * FROW + k0;
          const short* bp = Bi + (nt * 16 + l15) * FROW + k0;
          ah = *(const bf16x8*)ap;  al = *(const bf16x8*)(ap + 96);
          bh = *(const bf16x8*)bp;  bl = *(const bf16x8*)(bp + 96);
        }
        acc = MFMA(ah, bh, acc, 0, 0, 0);
        acc = MFMA(al, bh, acc, 0, 0, 0);
        acc = MFMA(ah, bl, acc, 0, 0, 0);
      }
      const int n = nt * 16 + l15;
      const int rowb = mt * 16 + kg * 4;
      short4 hs, ls;
#pragma unroll
      for (int r = 0; r < 4; ++r) {
        float v = acc[r];
        short hi = f2bf(v);
        short lo = f2bf(v - bf2f(hi));
        DA[(rowb + r) * FROW + n] = hi;
        DA[(rowb + r) * FROW + 96 + n] = lo;
        ((short*)&hs)[r] = hi;
        ((short*)&ls)[r] = lo;
      }
      *(short4*)(DB + n * FROW + rowb) = hs;
      *(short4*)(DB + n * FROW + 96 + rowb) = ls;
    }
    __syncthreads();
  };

  const int h = 31 - __clz(t);
  for (int bit = h - 1; bit >= 0; --bit) {
    mm(curA, curB, nxtA, nxtB);                               // square
    { short* p;
      p = curA; curA = nxtA; nxtA = p;
      p = curB; curB = nxtB; nxtB = p; }
    if ((t >> bit) & 1) {
      mm(kA, curB, nxtA, nxtB);                               // K * cur
      { short* p;
        p = curA; curA = nxtA; nxtA = p;
        p = curB; curB = nxtB; nxtB = p; }
    }
  }

  // hi/lo B-frag table for ypred: B[k][n] = (K^t)[n][k] = Aimg[n][k]
  short* kt = ws + KTAB + t * KSLOT;
  for (int s = tid; s < 960; s += 512) {
    int f = s >> 6, ln = s & 63;            // f = kk*5 + nt
    int kk = f / 5, nt = f % 5;
    int k0 = kk * 32 + (ln >> 4) * 8;
    int n  = nt * 16 + (ln & 15);
    bf16x8 h8 = {}, l8 = {};
    if (k0 < 80) {
      const short* ap = curA + n * FROW + k0;
      h8 = *(const bf16x8*)ap;
      l8 = *(const bf16x8*)(ap + 96);
    }
    *(bf16x8*)(kt + f * 512 + ln * 8) = h8;
    *(bf16x8*)(kt + 7680 + f * 512 + ln * 8) = l8;
  }
}

// ---------------------------------------------------------------------------
// MLP v5: one block = ONE batch row (64 tokens), 256 threads = 4 waves.
// Same swapped-operand inner shape as v4 (D = W x act^T, 4mt x 4nt acc),
// but 4 independent blocks/CU (LDS 33.8 KB) instead of 2: four
// unsynchronized barrier groups per CU -> barrier drains of one block are
// hidden by the other three. Occupancy still 16 waves/CU.
// Wave split GEMM1/2: mg = w (4 mtiles), all 4 token tiles per wave.
// GEMM3: mt3 = w (1 mtile), all 4 token tiles.
// ---------------------------------------------------------------------------
__global__ __launch_bounds__(256, 4) void mlp_kernel(const float* __restrict__ x,
                                                     const float* __restrict__ b1g,
                                                     const float* __restrict__ b2g,
                                                     const short* __restrict__ ws,
                                                     float* __restrict__ y) {
  extern __shared__ char smem[];
  short* h1s = (short*)smem;            // [64][264]; h2 overlays after barrier

  const int tid  = threadIdx.x;
  const int lane = tid & 63;
  const int w    = tid >> 6;            // 0..3
  const int l15  = lane & 15;
  const int kg   = lane >> 4;
  const long b   = blockIdx.x;          // 1 batch row each

  const short* W2f = ws;
  const short* W3f = ws + 65536;
  const short* W1f = ws + 81920;

  const float4 xv = ((const float4*)(x + b * 1024))[tid];   // for y epilogue

  // ---- x B-frags (x^T): lane holds x[tok][k0..k0+7], tok = col ----
  bf16x8 xf[4];
#pragma unroll
  for (int j = 0; j < 4; ++j) {
    const int tok = j * 16 + l15;
    bf16x8 f = {};
    if (kg < 2) {
      const float4* p = (const float4*)(x + (b * 64 + tok) * 16 + kg * 8);
      f = pack8(p[0], p[1]);
    }
    xf[j] = f;
  }

  // ---- GEMM1: D = W1 x x^T -> h1[tok][h] via packed b64 stores ----
#pragma unroll
  for (int i = 0; i < 4; ++i) {
    const int mt = w * 4 + i;
    const bf16x8 wa = *(const bf16x8*)(W1f + (mt * 64 + lane) * 8);
    const float4 bias = *(const float4*)(b1g + mt * 16 + kg * 4);
#pragma unroll
    for (int j = 0; j < 4; ++j) {
      f32x4 c = {0.f, 0.f, 0.f, 0.f};
      c = MFMA(wa, xf[j], c, 0, 0, 0);
      const int tok = j * 16 + l15;
      float v0 = c[0] + bias.x; v0 = v0 > 0.f ? v0 : 0.f;
      float v1 = c[1] + bias.y; v1 = v1 > 0.f ? v1 : 0.f;
      float v2 = c[2] + bias.z; v2 = v2 > 0.f ? v2 : 0.f;
      float v3 = c[3] + bias.w; v3 = v3 > 0.f ? v3 : 0.f;
      short4 st = {f2bf(v0), f2bf(v1), f2bf(v2), f2bf(v3)};
      *(short4*)(h1s + tok * 264 + mt * 16 + kg * 4) = st;
    }
  }
  __syncthreads();

  // ---- GEMM2: D = W2 x h1^T; K=256; acc 4mt x 4nt ----
  f32x4 acc2[4][4];
#pragma unroll
  for (int i = 0; i < 4; ++i)
#pragma unroll
    for (int j = 0; j < 4; ++j) acc2[i][j] = (f32x4){0.f, 0.f, 0.f, 0.f};

#pragma unroll 2
  for (int kk = 0; kk < 8; ++kk) {
    bf16x8 wa[4], hb[4];
#pragma unroll
    for (int i = 0; i < 4; ++i)
      wa[i] = *(const bf16x8*)(W2f + ((kk * 16 + w * 4 + i) * 64 + lane) * 8);
#pragma unroll
    for (int j = 0; j < 4; ++j)
      hb[j] = *(const bf16x8*)(h1s + (j * 16 + l15) * 264 + kk * 32 + kg * 8);
#pragma unroll
    for (int i = 0; i < 4; ++i)
#pragma unroll
      for (int j = 0; j < 4; ++j)
        acc2[i][j] = MFMA(wa[i], hb[j], acc2[i][j], 0, 0, 0);
  }
  __syncthreads();   // all h1 reads done -> overlay h2

#pragma unroll
  for (int i = 0; i < 4; ++i) {
    const int mt = w * 4 + i;
    const float4 bias = *(const float4*)(b2g + mt * 16 + kg * 4);
#pragma unroll
    for (int j = 0; j < 4; ++j) {
      const int tok = j * 16 + l15;
      float v0 = acc2[i][j][0] + bias.x; v0 = v0 > 0.f ? v0 : 0.f;
      float v1 = acc2[i][j][1] + bias.y; v1 = v1 > 0.f ? v1 : 0.f;
      float v2 = acc2[i][j][2] + bias.z; v2 = v2 > 0.f ? v2 : 0.f;
      float v3 = acc2[i][j][3] + bias.w; v3 = v3 > 0.f ? v3 : 0.f;
      short4 st = {f2bf(v0), f2bf(v1), f2bf(v2), f2bf(v3)};
      *(short4*)(h1s + tok * 264 + mt * 16 + kg * 4) = st;
    }
  }
  __syncthreads();

  // ---- GEMM3: D = W3 x h2^T; y stored straight from registers ----
  f32x4 acc3[4];
#pragma unroll
  for (int j = 0; j < 4; ++j) acc3[j] = (f32x4){0.f, 0.f, 0.f, 0.f};
#pragma unroll 2
  for (int kk = 0; kk < 8; ++kk) {
    const bf16x8 wa = *(const bf16x8*)(W3f + ((kk * 4 + w) * 64 + lane) * 8);
#pragma unroll
    for (int j = 0; j < 4; ++j) {
      const bf16x8 hb =
          *(const bf16x8*)(h1s + (j * 16 + l15) * 264 + kk * 32 + kg * 8);
      acc3[j] = MFMA(wa, hb, acc3[j], 0, 0, 0);
    }
  }

  // y x-part: token = tid>>2, floats (tid&3)*4..+3 (exact f32 from regs)
  *(float4*)(y + (b * 64 + (tid >> 2)) * 80 + (tid & 3) * 4) = xv;
  // y g-part: one float4 per tile (4 consecutive lat units of one token)
#pragma unroll
  for (int j = 0; j < 4; ++j) {
    const int tok = j * 16 + l15;
    *(float4*)(y + (b * 64 + tok) * 80 + 16 + w * 16 + kg * 4) =
        *(float4*)&acc3[j];
  }
}

// ---------------------------------------------------------------------------
// ypred v3: ONE t per block (grid = 16 batch-chunks x 64 t), 512 thr.
// 4 blocks/CU keeps the write queues full (per-CU write-BW bound).
// Wave w owns M-tiles {2w, 2w+1}; A hi/lo frags built per block; B-frags
// read directly from the precomputed hi/lo table. t=0 blocks do the copy.
// ---------------------------------------------------------------------------
__global__ __launch_bounds__(512, 4) void ypred_kernel(const short* __restrict__ ws,
                                                       const float* __restrict__ y,
                                                       float* __restrict__ yp) {
  const int tid  = threadIdx.x;
  const int lane = tid & 63;
  const int w    = tid >> 6;
  const int m16  = lane & 15;
  const int kg   = lane >> 4;
  const int bc   = blockIdx.x & 15;
  const int t    = blockIdx.x >> 4;        // 0..63
  const long b0  = (long)bc * 256;

  if (t == 0) {
    for (int i = tid; i < 5120; i += 512) {
      int r = i / 20, q = (i % 20) * 4;
      *(float4*)(yp + (b0 + r) * YROW + q) = *(const float4*)(y + (b0 + r) * YROW + q);
    }
    return;
  }

  // Build A hi/lo fragments from y0 (2 mt x 3 kk)
  bf16x8 ah[2][3], al[2][3];
#pragma unroll
  for (int m = 0; m < 2; ++m) {
#pragma unroll
    for (int kk = 0; kk < 3; ++kk) {
      const int k0 = kk * 32 + kg * 8;
      bf16x8 fh = {}, fl = {};
      if (k0 < 80) {
        const float4* p =
            (const float4*)(y + (b0 + (2 * w + m) * 16 + m16) * YROW + k0);
        split8(p[0], p[1], fh, fl);
      }
      ah[m][kk] = fh;
      al[m][kk] = fl;
    }
  }

  const short* kt = ws + KTAB + t * KSLOT;
  f32x4 acc[2][5];
#pragma unroll
  for (int m = 0; m < 2; ++m)
#pragma unroll
    for (int nt = 0; nt < 5; ++nt) acc[m][nt] = (f32x4){0.f, 0.f, 0.f, 0.f};

#pragma unroll
  for (int kk = 0; kk < 3; ++kk) {
#pragma unroll
    for (int nt = 0; nt < 5; ++nt) {
      const bf16x8 bh = *(const bf16x8*)(kt + ((kk * 5 + nt) * 64 + lane) * 8);
      const bf16x8 bl = *(const bf16x8*)(kt + 7680 + ((kk * 5 + nt) * 64 + lane) * 8);
#pragma unroll
      for (int m = 0; m < 2; ++m) {
        acc[m][nt] = MFMA(ah[m][kk], bh, acc[m][nt], 0, 0, 0);
        acc[m][nt] = MFMA(al[m][kk], bh, acc[m][nt], 0, 0, 0);
        acc[m][nt] = MFMA(ah[m][kk], bl, acc[m][nt], 0, 0, 0);
      }
    }
  }
#pragma unroll
  for (int m = 0; m < 2; ++m)
#pragma unroll
    for (int nt = 0; nt < 5; ++nt)
#pragma unroll
      for (int r = 0; r < 4; ++r)
        yp[(b0 + (2 * w + m) * 16 + kg * 4 + r) * YROW + (long)t * 80 + nt * 16 + m16] =
            acc[m][nt][r];
}

extern "C" void kernel_launch(void* const* d_in, const int* in_sizes, int n_in,
                              void* d_out, int out_size, void* d_ws, size_t ws_size,
                              hipStream_t stream) {
  const float* x  = (const float*)d_in[0];
  const float* W1 = (const float*)d_in[1];
  const float* b1 = (const float*)d_in[2];
  const float* W2 = (const float*)d_in[3];
  const float* b2 = (const float*)d_in[4];
  const float* W3 = (const float*)d_in[5];
  const float* Kg = (const float*)d_in[6];
  float* y  = (float*)d_out;
  float* yp = y + (long)NB * YROW;
  short* ws = (short*)d_ws;

  prep_kernel<<<256, 256, 0, stream>>>(W1, W2, W3, ws);
  kpow_kernel<<<63, 512, 5 * FIMG_B, stream>>>(Kg, ws);
  mlp_kernel<<<NB, 256, 33792, stream>>>(x, b1, b2, ws, y);
  ypred_kernel<<<16 * 64, 512, 0, stream>>>(ws, y, yp);
}